// Round 7
// baseline (375.213 us; speedup 1.0000x reference)
//
#include <hip/hip_runtime.h>

typedef short s16x8 __attribute__((ext_vector_type(8)));
typedef float f32x4 __attribute__((ext_vector_type(4)));
typedef float f32x2 __attribute__((ext_vector_type(2)));

#define TILE 2048   // edges per block: hist kernel
#define TILE2 8192  // edges per block: scatter kernel (fat segments)

// ---------- bf16 helpers (bit-level, RNE) ----------
__device__ __forceinline__ unsigned int brne(float f) {
    unsigned int u = __float_as_uint(f);
    return (u + 0x7FFFu + ((u >> 16) & 1u)) >> 16;   // bf16 bits in low 16
}
__device__ __forceinline__ float blo(unsigned int u) { return __uint_as_float(u << 16); }
__device__ __forceinline__ float bhi(unsigned int u) { return __uint_as_float(u & 0xFFFF0000u); }

// packed f32x2 -> bf16x2 via HW cvt (RNE)
__device__ __forceinline__ unsigned int pk_bf16(float lo, float hi) {
    unsigned int r;
    asm("v_cvt_pk_bf16_f32 %0, %1, %2" : "=v"(r) : "v"(lo), "v"(hi));
    return r;
}

// packed 2xf32 FMA (VOP3P)
__device__ __forceinline__ void pkfma(f32x2& a, const f32x2 x, const f32x2 w) {
    asm("v_pk_fma_f32 %0, %1, %2, %0" : "+v"(a) : "v"(x), "v"(w));
}

// accumulate 8 bf16 lanes of a uint4 row piece into 4 packed f32x2
__device__ __forceinline__ void acc8p(f32x2* a, const uint4 u, const f32x2 w2) {
    pkfma(a[0], (f32x2){blo(u.x), bhi(u.x)}, w2);
    pkfma(a[1], (f32x2){blo(u.y), bhi(u.y)}, w2);
    pkfma(a[2], (f32x2){blo(u.z), bhi(u.z)}, w2);
    pkfma(a[3], (f32x2){blo(u.w), bhi(u.w)}, w2);
}

// packed accumulate: 16 fp8 of a uint4 into 8 f32x2 accumulators
__device__ __forceinline__ void acc16p(f32x2* a, const uint4 u, const f32x2 w2) {
    pkfma(a[0], __builtin_amdgcn_cvt_pk_f32_fp8((int)u.x, false), w2);
    pkfma(a[1], __builtin_amdgcn_cvt_pk_f32_fp8((int)u.x, true),  w2);
    pkfma(a[2], __builtin_amdgcn_cvt_pk_f32_fp8((int)u.y, false), w2);
    pkfma(a[3], __builtin_amdgcn_cvt_pk_f32_fp8((int)u.y, true),  w2);
    pkfma(a[4], __builtin_amdgcn_cvt_pk_f32_fp8((int)u.z, false), w2);
    pkfma(a[5], __builtin_amdgcn_cvt_pk_f32_fp8((int)u.z, true),  w2);
    pkfma(a[6], __builtin_amdgcn_cvt_pk_f32_fp8((int)u.w, false), w2);
    pkfma(a[7], __builtin_amdgcn_cvt_pk_f32_fp8((int)u.w, true),  w2);
}

// ---------------- binned CSR build ----------------
// bucket = dst >> 8 (256 nodes per bucket); dense bucket regions.

// bucket hist + global deg atomics (blocks [0,nbt)) + weight transposes (>= nbt)
__global__ void k_bhist_deg_tw(const int* __restrict__ dst, int* __restrict__ bcnt,
                               int* __restrict__ deg, int e, int nb, int nbt,
                               const float* __restrict__ W1, const float* __restrict__ W2,
                               unsigned short* __restrict__ W1t, unsigned short* __restrict__ W2t) {
    const int tid = threadIdx.x;
    if ((int)blockIdx.x >= nbt) {
        const int t = ((int)blockIdx.x - nbt) * 256 + tid;
        if (t < 65536) {
            const int k = t >> 8, nn = t & 255;
            W1t[nn * 256 + k] = (unsigned short)brne(W1[t]);
        } else {
            const int u = t - 65536;
            const int k = u >> 7, nn = u & 127;
            W2t[nn * 256 + k] = (unsigned short)brne(W2[u]);
        }
        return;
    }
    __shared__ int h[256];
    h[tid] = 0;
    __syncthreads();
    const int base = blockIdx.x * TILE + tid;
#pragma unroll
    for (int k = 0; k < 8; k++) {
        const int i = base + k * 256;
        if (i < e) {
            const int d = dst[i];
            atomicAdd(&h[d >> 8], 1);
            atomicAdd(&deg[d], 1);
        }
    }
    __syncthreads();
    if (tid < nb && h[tid]) atomicAdd(&bcnt[tid], h[tid]);
}

// scatter into DENSE buckets; TILE2 edges/block -> fat per-bucket segments.
// pass A: dst-only hist -> global reservation; pass B: re-read + scatter.
__global__ void k_bscatter8(const int* __restrict__ src, const int* __restrict__ dst,
                            const int* __restrict__ bcnt, int* __restrict__ bcur,
                            uint2* __restrict__ eb, int e, int nb) {
    __shared__ int sh[256], h[256], base2[256], h2[256];
    const int tid = threadIdx.x;
    // inline exclusive scan of bcnt -> bucket base (redundant per block)
    const int v = (tid < nb) ? bcnt[tid] : 0;
    int x = v;
    sh[tid] = x;
    __syncthreads();
    for (int off = 1; off < 256; off <<= 1) {
        const int t = (tid >= off) ? sh[tid - off] : 0;
        __syncthreads();
        if (tid >= off) { x += t; sh[tid] = x; }
        __syncthreads();
    }
    const int sbase = x - v;   // exclusive base for bucket `tid`
    h[tid] = 0; h2[tid] = 0;
    __syncthreads();
    const int beg = blockIdx.x * TILE2;
    const int fin = min(beg + TILE2, e);
    // pass A: count per bucket for this block
    for (int i = beg + tid; i < fin; i += 256)
        atomicAdd(&h[dst[i] >> 8], 1);
    __syncthreads();
    // reservation: bucket-relative cursor + dense bucket base
    if (h[tid]) base2[tid] = sbase + atomicAdd(&bcur[tid], h[tid]);
    __syncthreads();
    // pass B: re-read (L2-hot) and scatter into contiguous segment
    for (int i = beg + tid; i < fin; i += 256) {
        const int s = src[i], d = dst[i];
        const int b = d >> 8;
        const int off = atomicAdd(&h2[b], 1);
        eb[base2[b] + off] = make_uint2((unsigned)s, (unsigned)d);
    }
}

// per-256-node-chunk exclusive scan of deg -> local rowptr + chunk totals + dinv.
// PREW: writes es pad entries.
template <bool PREW>
__global__ void k_scan1(const int* __restrict__ deg, int* __restrict__ rowptr,
                        int* __restrict__ part, float* __restrict__ dinv,
                        void* __restrict__ esv, int n, int e) {
    __shared__ int sh[256];
    const int tid = threadIdx.x, b = blockIdx.x;
    const int node = b * 256 + tid;
    const int v = (node < n) ? deg[node] : 0;
    if (node < n) dinv[node] = rsqrtf((float)(v + 1));  // deg includes self-loop
    int x = v;
    sh[tid] = x;
    __syncthreads();
    for (int off = 1; off < 256; off <<= 1) {
        const int t = (tid >= off) ? sh[tid - off] : 0;
        __syncthreads();
        if (tid >= off) { x += t; sh[tid] = x; }
        __syncthreads();
    }
    if (node <= n) rowptr[node] = x - v;   // chunk-local exclusive offset
    if (tid == 255) part[b] = x;           // chunk total
    if (PREW && b == 0 && tid < 64) ((int2*)esv)[e + tid] = make_int2(0, 0);
}

// inline scans (bcnt -> eb base; part -> rowptr prefix) -> placement.
template <bool PREW>
__global__ void k_place3(const uint2* __restrict__ eb, const int* __restrict__ bcnt,
                         int* __restrict__ rowptr, const int* __restrict__ part,
                         const float* __restrict__ dinv, void* __restrict__ esv,
                         int n, int nb) {
    __shared__ int sh[256], rp[256], offs[256];
    __shared__ float sdv[256];
    const int tid = threadIdx.x, b = blockIdx.x;
    // scan 1: bcnt -> dense eb bucket base for bucket `b`
    const int cv = (tid < nb) ? bcnt[tid] : 0;
    int x = cv;
    sh[tid] = x;
    __syncthreads();
    for (int off = 1; off < 256; off <<= 1) {
        const int t = (tid >= off) ? sh[tid - off] : 0;
        __syncthreads();
        if (tid >= off) { x += t; sh[tid] = x; }
        __syncthreads();
    }
    const int ebBase = (b > 0) ? sh[b - 1] : 0;
    const int cnt = bcnt[b];
    __syncthreads();
    // scan 2: part -> global rowptr prefix
    int y = (tid < nb) ? part[tid] : 0;
    sh[tid] = y;
    __syncthreads();
    for (int off = 1; off < 256; off <<= 1) {
        const int t = (tid >= off) ? sh[tid - off] : 0;
        __syncthreads();
        if (tid >= off) { y += t; sh[tid] = y; }
        __syncthreads();
    }
    const int prefix = (b > 0) ? sh[b - 1] : 0;
    const int node = b * 256 + tid;
    int rg = 0;
    if (node <= n) {
        rg = rowptr[node] + prefix;
        rowptr[node] = rg;                 // now global (props read this)
    }
    rp[tid] = rg;
    offs[tid] = 0;
    if (PREW) sdv[tid] = (node < n) ? dinv[node] : 0.f;
    __syncthreads();
    if (PREW) {
        int2* es2 = (int2*)esv;
        for (int i = tid; i < cnt; i += 256) {
            const uint2 ed = eb[ebBase + i];
            const int sI = (int)ed.x, d = (int)ed.y & 255;
            const float w = dinv[sI] * sdv[d];
            const int local = atomicAdd(&offs[d], 1);
            es2[rp[d] + local] = make_int2(sI, __float_as_int(w));
        }
    } else {
        int* es1 = (int*)esv;
        for (int i = tid; i < cnt; i += 256) {
            const uint2 ed = eb[ebBase + i];
            const int d = (int)ed.y & 255;
            const int local = atomicAdd(&offs[d], 1);
            es1[rp[d] + local] = (int)ed.x;
        }
    }
}

// ---------------- MFMA GEMM: C[M,Nc] = A[M,256] @ Bt[Nc,256]^T ----------------
// Double-buffered LDS, 1 barrier per K-step.
#define LP 40
template <bool AF32, bool FP8OUT>
__global__ __launch_bounds__(256) void k_gemm(const void* __restrict__ Av,
                                              const unsigned short* __restrict__ Bt,
                                              void* __restrict__ Cout,
                                              int M, int Nc) {
    __shared__ unsigned short As[2][128 * LP];
    __shared__ unsigned short Bs[2][128 * LP];

    const int tid = threadIdx.x;
    const int wave = tid >> 6, lane = tid & 63;
    const int wm = (wave >> 1) * 64, wn = (wave & 1) * 64;
    const int l15 = lane & 15, quad = lane >> 4;
    const int mBase = blockIdx.x * 128, nBase = blockIdx.y * 128;

    f32x4 acc[4][4];
#pragma unroll
    for (int i = 0; i < 4; i++)
#pragma unroll
        for (int j = 0; j < 4; j++) acc[i][j] = (f32x4){0.f, 0.f, 0.f, 0.f};

    const int r0 = tid >> 2, kc0 = tid & 3;       // staged rows r0 and r0+64
    int am0 = mBase + r0;      if (am0 >= M) am0 = M - 1;
    int am1 = mBase + r0 + 64; if (am1 >= M) am1 = M - 1;

    const uint4* Ap0; const uint4* Ap1; const float4* Af0; const float4* Af1;
    if (AF32) {
        Af0 = (const float4*)Av + (size_t)am0 * 64 + kc0 * 2;
        Af1 = (const float4*)Av + (size_t)am1 * 64 + kc0 * 2;
    } else {
        Ap0 = (const uint4*)Av + (size_t)am0 * 32 + kc0;
        Ap1 = (const uint4*)Av + (size_t)am1 * 32 + kc0;
    }
    const uint4* Bp0 = (const uint4*)Bt + (size_t)(nBase + r0) * 32 + kc0;
    const uint4* Bp1 = (const uint4*)Bt + (size_t)(nBase + r0 + 64) * 32 + kc0;

    uint4 a0, a1, b0, b1;
    auto LOAD = [&](int kt) {
        if (AF32) {
            const float4 l0 = Af0[kt * 8], h0 = Af0[kt * 8 + 1];
            const float4 l1 = Af1[kt * 8], h1 = Af1[kt * 8 + 1];
            a0.x = pk_bf16(l0.x, l0.y); a0.y = pk_bf16(l0.z, l0.w);
            a0.z = pk_bf16(h0.x, h0.y); a0.w = pk_bf16(h0.z, h0.w);
            a1.x = pk_bf16(l1.x, l1.y); a1.y = pk_bf16(l1.z, l1.w);
            a1.z = pk_bf16(h1.x, h1.y); a1.w = pk_bf16(h1.z, h1.w);
        } else {
            a0 = Ap0[kt * 4];
            a1 = Ap1[kt * 4];
        }
        b0 = Bp0[kt * 4];
        b1 = Bp1[kt * 4];
    };
    auto STORE = [&](int buf) {
        *(uint4*)&As[buf][r0 * LP + kc0 * 8] = a0;
        *(uint4*)&As[buf][(r0 + 64) * LP + kc0 * 8] = a1;
        *(uint4*)&Bs[buf][r0 * LP + kc0 * 8] = b0;
        *(uint4*)&Bs[buf][(r0 + 64) * LP + kc0 * 8] = b1;
    };

    LOAD(0);
    STORE(0);
    __syncthreads();
    for (int kt = 0; kt < 8; ++kt) {
        const int cur = kt & 1;
        if (kt < 7) LOAD(kt + 1);
        s16x8 af[4], bf[4];
#pragma unroll
        for (int i = 0; i < 4; i++)
            af[i] = *(const s16x8*)&As[cur][(wm + i * 16 + l15) * LP + quad * 8];
#pragma unroll
        for (int j = 0; j < 4; j++)
            bf[j] = *(const s16x8*)&Bs[cur][(wn + j * 16 + l15) * LP + quad * 8];
        if (kt < 7) STORE(cur ^ 1);
#pragma unroll
        for (int i = 0; i < 4; i++)
#pragma unroll
            for (int j = 0; j < 4; j++)
                acc[i][j] = __builtin_amdgcn_mfma_f32_16x16x32_bf16(af[i], bf[j], acc[i][j], 0, 0, 0);
        __syncthreads();
    }

#pragma unroll
    for (int i = 0; i < 4; i++) {
        const int rowb = mBase + wm + i * 16 + quad * 4;
#pragma unroll
        for (int j = 0; j < 4; j++) {
            const int col = nBase + wn + j * 16 + l15;
#pragma unroll
            for (int r = 0; r < 4; r += 2) {
                if (FP8OUT) {
                    const unsigned int pk = __builtin_amdgcn_cvt_pk_fp8_f32(
                        acc[i][j][r], acc[i][j][r + 1], 0, false);
                    if (rowb + r < M)
                        ((unsigned char*)Cout)[(size_t)(rowb + r) * Nc + col] =
                            (unsigned char)pk;
                    if (rowb + r + 1 < M)
                        ((unsigned char*)Cout)[(size_t)(rowb + r + 1) * Nc + col] =
                            (unsigned char)(pk >> 8);
                } else {
                    const unsigned int pk = pk_bf16(acc[i][j][r], acc[i][j][r + 1]);
                    if (rowb + r < M)
                        ((unsigned short*)Cout)[(size_t)(rowb + r) * Nc + col] =
                            (unsigned short)pk;
                    if (rowb + r + 1 < M)
                        ((unsigned short*)Cout)[(size_t)(rowb + r + 1) * Nc + col] =
                            (unsigned short)(pk >> 16);
                }
            }
        }
    }
}

// ---------------- propagation ----------------
// Quarter-wave per edge, 4-deep gather pipeline, branchless weight-zeroed tail.

template <bool PREW>
__global__ void k_prop256f8(const uint4* __restrict__ X4,
                            const int* __restrict__ rowptr,
                            const void* __restrict__ esv,
                            const float* __restrict__ dinv,
                            const float* __restrict__ bias,
                            uint4* __restrict__ Y4, int n) {
    const int wid = (int)((blockIdx.x * blockDim.x + threadIdx.x) >> 6);
    const int lane = threadIdx.x & 63;
    const int quad = lane >> 4, l16 = lane & 15;
    if (wid >= n) return;
    const float dd = dinv[wid];
    const int2* es2 = (const int2*)esv;
    const int*  es1 = (const int*)esv;
    f32x2 a[8];
#pragma unroll
    for (int k = 0; k < 8; k++) a[k] = (f32x2){0.f, 0.f};

    const int beg = rowptr[wid], end = rowptr[wid + 1];
    int j = beg + quad;

    auto EDGE = [&](int jj, int& s, float& w) {
        const bool v = jj < end;
        const int idx = v ? jj : beg;   // in-row clamp (hot line)
        if (PREW) {
            const int2 p = es2[idx];
            s = p.x;
            w = v ? __int_as_float(p.y) : 0.f;
        } else {
            s = es1[v ? jj : 0];
            w = v ? dinv[s] * dd : 0.f;
        }
    };

    int s0, s1, s2, s3;
    float w0, w1, w2, w3;
    EDGE(j, s0, w0); EDGE(j + 4, s1, w1); EDGE(j + 8, s2, w2); EDGE(j + 12, s3, w3);

    if (quad == 0) {
        const uint4 v = X4[(size_t)wid * 16 + l16];
        acc16p(a, v, (f32x2){dd * dd, dd * dd});
    }

    while (j + 12 < end) {
        const uint4 u0 = X4[(size_t)s0 * 16 + l16];
        const uint4 u1 = X4[(size_t)s1 * 16 + l16];
        const uint4 u2 = X4[(size_t)s2 * 16 + l16];
        const uint4 u3 = X4[(size_t)s3 * 16 + l16];
        j += 16;
        int t0, t1, t2, t3;
        float x0, x1, x2, x3;
        EDGE(j, t0, x0); EDGE(j + 4, t1, x1); EDGE(j + 8, t2, x2); EDGE(j + 12, t3, x3);
        acc16p(a, u0, (f32x2){w0, w0});
        acc16p(a, u1, (f32x2){w1, w1});
        acc16p(a, u2, (f32x2){w2, w2});
        acc16p(a, u3, (f32x2){w3, w3});
        s0 = t0; s1 = t1; s2 = t2; s3 = t3;
        w0 = x0; w1 = x1; w2 = x2; w3 = x3;
    }
    {
        const uint4 u0 = X4[(size_t)s0 * 16 + l16];
        const uint4 u1 = X4[(size_t)s1 * 16 + l16];
        const uint4 u2 = X4[(size_t)s2 * 16 + l16];
        acc16p(a, u0, (f32x2){w0, w0});
        acc16p(a, u1, (f32x2){w1, w1});
        acc16p(a, u2, (f32x2){w2, w2});
    }
#pragma unroll
    for (int k = 0; k < 8; k++) {
        a[k][0] += __shfl_xor(a[k][0], 16);
        a[k][1] += __shfl_xor(a[k][1], 16);
        a[k][0] += __shfl_xor(a[k][0], 32);
        a[k][1] += __shfl_xor(a[k][1], 32);
    }
    if (quad == 0) {
        const float4* bp = (const float4*)bias + l16 * 4;
#pragma unroll
        for (int q = 0; q < 4; q++) {
            const float4 b = bp[q];
            a[2 * q][0]     = fmaxf(a[2 * q][0] + b.x, 0.f);
            a[2 * q][1]     = fmaxf(a[2 * q][1] + b.y, 0.f);
            a[2 * q + 1][0] = fmaxf(a[2 * q + 1][0] + b.z, 0.f);
            a[2 * q + 1][1] = fmaxf(a[2 * q + 1][1] + b.w, 0.f);
        }
        uint4 p0, p1;
        p0.x = pk_bf16(a[0][0], a[0][1]);
        p0.y = pk_bf16(a[1][0], a[1][1]);
        p0.z = pk_bf16(a[2][0], a[2][1]);
        p0.w = pk_bf16(a[3][0], a[3][1]);
        p1.x = pk_bf16(a[4][0], a[4][1]);
        p1.y = pk_bf16(a[5][0], a[5][1]);
        p1.z = pk_bf16(a[6][0], a[6][1]);
        p1.w = pk_bf16(a[7][0], a[7][1]);
        Y4[(size_t)wid * 32 + l16 * 2] = p0;
        Y4[(size_t)wid * 32 + l16 * 2 + 1] = p1;
    }
}

template <bool PREW>
__global__ void k_prop128b(const uint4* __restrict__ X4,
                           const int* __restrict__ rowptr,
                           const void* __restrict__ esv,
                           const float* __restrict__ dinv,
                           const float* __restrict__ bias,
                           float* __restrict__ Yout, int n) {
    const int wid = (int)((blockIdx.x * blockDim.x + threadIdx.x) >> 6);
    const int lane = threadIdx.x & 63;
    const int quad = lane >> 4, l16 = lane & 15;
    if (wid >= n) return;
    const float dd = dinv[wid];
    const int2* es2 = (const int2*)esv;
    const int*  es1 = (const int*)esv;
    f32x2 a[4];
#pragma unroll
    for (int k = 0; k < 4; k++) a[k] = (f32x2){0.f, 0.f};

    const int beg = rowptr[wid], end = rowptr[wid + 1];
    int j = beg + quad;

    auto EDGE = [&](int jj, int& s, float& w) {
        const bool v = jj < end;
        const int idx = v ? jj : beg;
        if (PREW) {
            const int2 p = es2[idx];
            s = p.x;
            w = v ? __int_as_float(p.y) : 0.f;
        } else {
            s = es1[v ? jj : 0];
            w = v ? dinv[s] * dd : 0.f;
        }
    };

    int s0, s1, s2, s3;
    float w0, w1, w2, w3;
    EDGE(j, s0, w0); EDGE(j + 4, s1, w1); EDGE(j + 8, s2, w2); EDGE(j + 12, s3, w3);

    if (quad == 0) {
        const uint4 v = X4[(size_t)wid * 16 + l16];
        acc8p(a, v, (f32x2){dd * dd, dd * dd});
    }

    while (j + 12 < end) {
        const uint4 u0 = X4[(size_t)s0 * 16 + l16];
        const uint4 u1 = X4[(size_t)s1 * 16 + l16];
        const uint4 u2 = X4[(size_t)s2 * 16 + l16];
        const uint4 u3 = X4[(size_t)s3 * 16 + l16];
        j += 16;
        int t0, t1, t2, t3;
        float x0, x1, x2, x3;
        EDGE(j, t0, x0); EDGE(j + 4, t1, x1); EDGE(j + 8, t2, x2); EDGE(j + 12, t3, x3);
        acc8p(a, u0, (f32x2){w0, w0});
        acc8p(a, u1, (f32x2){w1, w1});
        acc8p(a, u2, (f32x2){w2, w2});
        acc8p(a, u3, (f32x2){w3, w3});
        s0 = t0; s1 = t1; s2 = t2; s3 = t3;
        w0 = x0; w1 = x1; w2 = x2; w3 = x3;
    }
    {
        const uint4 u0 = X4[(size_t)s0 * 16 + l16];
        const uint4 u1 = X4[(size_t)s1 * 16 + l16];
        const uint4 u2 = X4[(size_t)s2 * 16 + l16];
        acc8p(a, u0, (f32x2){w0, w0});
        acc8p(a, u1, (f32x2){w1, w1});
        acc8p(a, u2, (f32x2){w2, w2});
    }
#pragma unroll
    for (int k = 0; k < 4; k++) {
        a[k][0] += __shfl_xor(a[k][0], 16);
        a[k][1] += __shfl_xor(a[k][1], 16);
        a[k][0] += __shfl_xor(a[k][0], 32);
        a[k][1] += __shfl_xor(a[k][1], 32);
    }
    if (quad == 0) {
        const float4 b0 = ((const float4*)bias)[l16 * 2];
        const float4 b1 = ((const float4*)bias)[l16 * 2 + 1];
        float4* op = (float4*)Yout + (size_t)wid * 32 + l16 * 2;
        op[0] = make_float4(a[0][0] + b0.x, a[0][1] + b0.y, a[1][0] + b0.z, a[1][1] + b0.w);
        op[1] = make_float4(a[2][0] + b1.x, a[2][1] + b1.y, a[3][0] + b1.z, a[3][1] + b1.w);
    }
}

extern "C" void kernel_launch(void* const* d_in, const int* in_sizes, int n_in,
                              void* d_out, int out_size, void* d_ws, size_t ws_size,
                              hipStream_t stream) {
    const float* x  = (const float*)d_in[0];
    const int*   ei = (const int*)d_in[1];
    const float* W1 = (const float*)d_in[2];
    const float* b1 = (const float*)d_in[3];
    const float* W2 = (const float*)d_in[4];
    const float* b2 = (const float*)d_in[5];
    float* out = (float*)d_out;

    const int n = in_sizes[0] / 256;  // 50000
    const int e = in_sizes[1] / 2;    // 1600000
    const int* src = ei;
    const int* dst = ei + e;
    const int nb = (n + 255) >> 8;    // 196 buckets (<=256 required)

    auto al = [](size_t v) { return (v + 511) & ~(size_t)511; };
    const size_t fixed = al(sizeof(float) * n) + al(sizeof(int) * (n + 1)) +
                         al(1024) + al(4ull * (512 + n)) +
                         al(2ull * 256 * 256) + al(2ull * 128 * 256) +
                         al((size_t)n * 256) + al(2ull * n * 256) + al(2ull * n * 128);
    const bool prew = (fixed + al(8ull * ((size_t)e + 64))) <= ws_size;

    char* wsp = (char*)d_ws;
    size_t off = 0;
    auto alloc = [&](size_t bytes) -> char* {
        char* p = wsp + off;
        off += (bytes + 511) & ~(size_t)511;
        return p;
    };
    float* dinv    = (float*)alloc(sizeof(float) * n);
    int*   rowptr  = (int*)alloc(sizeof(int) * (n + 1));
    int*   part    = (int*)alloc(1024);
    int*   bcd     = (int*)alloc(4ull * (512 + n));   // bcnt[256]|bcur[256]|deg[n]
    int*   bcnt    = bcd;
    int*   bcur    = bcd + 256;
    int*   deg     = bcd + 512;
    void*  es      = (void*)alloc(prew ? 8ull * ((size_t)e + 64) : 4ull * (size_t)e);
    unsigned short* W1t = (unsigned short*)alloc(2ull * 256 * 256); // [N][K]
    unsigned short* W2t = (unsigned short*)alloc(2ull * 128 * 256); // [N][K]
    unsigned char*  T1  = (unsigned char*)alloc((size_t)n * 256);   // x@W1 fp8
    unsigned short* H   = (unsigned short*)alloc(2ull * n * 256);   // relu(prop+b1) bf16
    unsigned short* T2  = (unsigned short*)alloc(2ull * n * 128);   // H@W2 bf16
    // eb (dense binned pairs, 8B*e = 12.8MB) aliases H (25.6MB):
    // build finishes (k_place3) before H is first written (prop256f8).
    uint2* eb = (uint2*)H;

    const int nb_t  = (e + TILE - 1) / TILE;      // 782 (hist)
    const int nb_t2 = (e + TILE2 - 1) / TILE2;    // 196 (scatter, fat segments)
    const int tw_b  = (65536 + 32768) / 256;      // 384 transpose blocks

    // ---- build: memset + 4 dispatches ----
    (void)hipMemsetAsync(bcd, 0, 4ull * (512 + n), stream);
    k_bhist_deg_tw<<<nb_t + tw_b, 256, 0, stream>>>(dst, bcnt, deg, e, nb, nb_t,
                                                    W1, W2, W1t, W2t);
    k_bscatter8<<<nb_t2, 256, 0, stream>>>(src, dst, bcnt, bcur, eb, e, nb);
    if (prew) {
        k_scan1<true><<<nb, 256, 0, stream>>>(deg, rowptr, part, dinv, es, n, e);
        k_place3<true><<<nb, 256, 0, stream>>>(eb, bcnt, rowptr, part, dinv, es, n, nb);
    } else {
        k_scan1<false><<<nb, 256, 0, stream>>>(deg, rowptr, part, dinv, es, n, e);
        k_place3<false><<<nb, 256, 0, stream>>>(eb, bcnt, rowptr, part, dinv, es, n, nb);
    }

    // ---- layer 1: T1 = fp8(x@W1) ----
    dim3 g1((n + 127) / 128, 2);
    k_gemm<true, true><<<g1, 256, 0, stream>>>(x, W1t, T1, n, 256);
    if (prew)
        k_prop256f8<true><<<(n + 3) / 4, 256, 0, stream>>>((const uint4*)T1, rowptr, es,
                                                           dinv, b1, (uint4*)H, n);
    else
        k_prop256f8<false><<<(n + 3) / 4, 256, 0, stream>>>((const uint4*)T1, rowptr, es,
                                                            dinv, b1, (uint4*)H, n);

    // ---- layer 2: T2 = bf16(H@W2); out = prop(T2)+b2 ----
    dim3 g2((n + 127) / 128, 1);
    k_gemm<false, false><<<g2, 256, 0, stream>>>(H, W2t, T2, n, 128);
    if (prew)
        k_prop128b<true><<<(n + 3) / 4, 256, 0, stream>>>((const uint4*)T2, rowptr, es,
                                                          dinv, b2, out, n);
    else
        k_prop128b<false><<<(n + 3) / 4, 256, 0, stream>>>((const uint4*)T2, rowptr, es,
                                                           dinv, b2, out, n);
}

// Round 8
// 331.034 us; speedup vs baseline: 1.1335x; 1.1335x over previous
//
#include <hip/hip_runtime.h>

typedef short s16x8 __attribute__((ext_vector_type(8)));
typedef float f32x4 __attribute__((ext_vector_type(4)));
typedef float f32x2 __attribute__((ext_vector_type(2)));

#define TILE 2048   // edges per block: hist kernel
#define TILE2 8192  // edges per block: scatter kernel (fat segments)

// ---------- bf16 helpers (bit-level, RNE) ----------
__device__ __forceinline__ unsigned int brne(float f) {
    unsigned int u = __float_as_uint(f);
    return (u + 0x7FFFu + ((u >> 16) & 1u)) >> 16;   // bf16 bits in low 16
}
__device__ __forceinline__ float blo(unsigned int u) { return __uint_as_float(u << 16); }
__device__ __forceinline__ float bhi(unsigned int u) { return __uint_as_float(u & 0xFFFF0000u); }

// packed f32x2 -> bf16x2 via HW cvt (RNE)
__device__ __forceinline__ unsigned int pk_bf16(float lo, float hi) {
    unsigned int r;
    asm("v_cvt_pk_bf16_f32 %0, %1, %2" : "=v"(r) : "v"(lo), "v"(hi));
    return r;
}

// packed 2xf32 FMA (VOP3P)
__device__ __forceinline__ void pkfma(f32x2& a, const f32x2 x, const f32x2 w) {
    asm("v_pk_fma_f32 %0, %1, %2, %0" : "+v"(a) : "v"(x), "v"(w));
}

// accumulate 8 bf16 lanes of a uint4 row piece into 4 packed f32x2
__device__ __forceinline__ void acc8p(f32x2* a, const uint4 u, const f32x2 w2) {
    pkfma(a[0], (f32x2){blo(u.x), bhi(u.x)}, w2);
    pkfma(a[1], (f32x2){blo(u.y), bhi(u.y)}, w2);
    pkfma(a[2], (f32x2){blo(u.z), bhi(u.z)}, w2);
    pkfma(a[3], (f32x2){blo(u.w), bhi(u.w)}, w2);
}

// packed accumulate: 16 fp8 of a uint4 into 8 f32x2 accumulators
__device__ __forceinline__ void acc16p(f32x2* a, const uint4 u, const f32x2 w2) {
    pkfma(a[0], __builtin_amdgcn_cvt_pk_f32_fp8((int)u.x, false), w2);
    pkfma(a[1], __builtin_amdgcn_cvt_pk_f32_fp8((int)u.x, true),  w2);
    pkfma(a[2], __builtin_amdgcn_cvt_pk_f32_fp8((int)u.y, false), w2);
    pkfma(a[3], __builtin_amdgcn_cvt_pk_f32_fp8((int)u.y, true),  w2);
    pkfma(a[4], __builtin_amdgcn_cvt_pk_f32_fp8((int)u.z, false), w2);
    pkfma(a[5], __builtin_amdgcn_cvt_pk_f32_fp8((int)u.z, true),  w2);
    pkfma(a[6], __builtin_amdgcn_cvt_pk_f32_fp8((int)u.w, false), w2);
    pkfma(a[7], __builtin_amdgcn_cvt_pk_f32_fp8((int)u.w, true),  w2);
}

// ---------------- binned CSR build ----------------
// bucket = dst >> 8 (256 nodes/bucket). eb entry packed: (dst&255)<<24 | src.
// es layout: bucket-local fixed-capacity regions; rowptr[node] = b*capE + off,
// row end = rowptr[node] + cnt[node]. No cross-bucket prefix needed.

// bucket hist via LDS (blocks [0,nbt)) + weight transposes (blocks >= nbt)
__global__ void k_bhist_tw(const int* __restrict__ dst, int* __restrict__ bcnt,
                           int e, int nb, int nbt,
                           const float* __restrict__ W1, const float* __restrict__ W2,
                           unsigned short* __restrict__ W1t, unsigned short* __restrict__ W2t) {
    const int tid = threadIdx.x;
    if ((int)blockIdx.x >= nbt) {
        const int t = ((int)blockIdx.x - nbt) * 256 + tid;
        if (t < 65536) {
            const int k = t >> 8, nn = t & 255;
            W1t[nn * 256 + k] = (unsigned short)brne(W1[t]);
        } else {
            const int u = t - 65536;
            const int k = u >> 7, nn = u & 127;
            W2t[nn * 256 + k] = (unsigned short)brne(W2[u]);
        }
        return;
    }
    __shared__ int h[256];
    h[tid] = 0;
    __syncthreads();
    const int base = blockIdx.x * TILE + tid;
#pragma unroll
    for (int k = 0; k < 8; k++) {
        const int i = base + k * 256;
        if (i < e) atomicAdd(&h[dst[i] >> 8], 1);
    }
    __syncthreads();
    if (tid < nb && h[tid]) atomicAdd(&bcnt[tid], h[tid]);
}

// scatter into DENSE buckets; TILE2 edges/block -> fat per-bucket segments.
// pass A: dst-only hist -> global reservation; pass B: re-read + packed scatter.
__global__ void k_bscatter8(const int* __restrict__ src, const int* __restrict__ dst,
                            const int* __restrict__ bcnt, int* __restrict__ bcur,
                            unsigned int* __restrict__ eb, int e, int nb) {
    __shared__ int sh[256], h[256], base2[256], h2[256];
    const int tid = threadIdx.x;
    // inline exclusive scan of bcnt -> dense bucket base (redundant per block)
    const int v = (tid < nb) ? bcnt[tid] : 0;
    int x = v;
    sh[tid] = x;
    __syncthreads();
    for (int off = 1; off < 256; off <<= 1) {
        const int t = (tid >= off) ? sh[tid - off] : 0;
        __syncthreads();
        if (tid >= off) { x += t; sh[tid] = x; }
        __syncthreads();
    }
    const int sbase = x - v;   // exclusive base for bucket `tid`
    h[tid] = 0; h2[tid] = 0;
    __syncthreads();
    const int beg = blockIdx.x * TILE2;
    const int fin = min(beg + TILE2, e);
    for (int i = beg + tid; i < fin; i += 256)
        atomicAdd(&h[dst[i] >> 8], 1);
    __syncthreads();
    if (h[tid]) base2[tid] = sbase + atomicAdd(&bcur[tid], h[tid]);
    __syncthreads();
    for (int i = beg + tid; i < fin; i += 256) {
        const int s = src[i], d = dst[i];
        const int b = d >> 8;
        const int off = atomicAdd(&h2[b], 1);
        eb[base2[b] + off] = ((unsigned)(d & 255) << 24) | (unsigned)s;
    }
}

// fused: per-bucket node hist + dinv + cnt + local scan + placement (ONE eb read)
__global__ void k_merged(const unsigned int* __restrict__ eb, const int* __restrict__ bcnt,
                         int* __restrict__ rowptr, int* __restrict__ cnt,
                         float* __restrict__ dinv, int* __restrict__ es,
                         int n, int nb, int capE) {
    __shared__ int sh[256], c[256], rp[256], offs[256];
    const int tid = threadIdx.x, b = blockIdx.x;
    // inline exclusive scan of bcnt -> dense eb base for bucket b
    const int v0 = (tid < nb) ? bcnt[tid] : 0;
    int x = v0;
    sh[tid] = x;
    __syncthreads();
    for (int off = 1; off < 256; off <<= 1) {
        const int t = (tid >= off) ? sh[tid - off] : 0;
        __syncthreads();
        if (tid >= off) { x += t; sh[tid] = x; }
        __syncthreads();
    }
    const int ebBase = (b > 0) ? sh[b - 1] : 0;
    const int cntB = bcnt[b];
    c[tid] = 0;
    __syncthreads();
    // node histogram within bucket
    for (int i = tid; i < cntB; i += 256)
        atomicAdd(&c[eb[ebBase + i] >> 24], 1);
    __syncthreads();
    const int v = c[tid];
    const int node = b * 256 + tid;
    if (node < n) {
        dinv[node] = rsqrtf((float)(v + 1));  // deg includes self-loop
        cnt[node] = v;
    }
    // local exclusive scan -> bucket-local rowptr
    int y = v;
    sh[tid] = y;
    __syncthreads();
    for (int off = 1; off < 256; off <<= 1) {
        const int t = (tid >= off) ? sh[tid - off] : 0;
        __syncthreads();
        if (tid >= off) { y += t; sh[tid] = y; }
        __syncthreads();
    }
    const int beg = b * capE + (y - v);
    if (node < n) rowptr[node] = beg;
    rp[tid] = beg;
    offs[tid] = 0;
    __syncthreads();
    // placement: src-only es, bucket-windowed writes
    for (int i = tid; i < cntB; i += 256) {
        const unsigned int u = eb[ebBase + i];
        const int d = (int)(u >> 24);
        const int local = atomicAdd(&offs[d], 1);
        es[rp[d] + local] = (int)(u & 0xFFFFFFu);
    }
}

// ---------------- MFMA GEMM: C[M,Nc] = A[M,256] @ Bt[Nc,256]^T ----------------
// Double-buffered LDS, 1 barrier per K-step.
#define LP 40
template <bool AF32, bool FP8OUT>
__global__ __launch_bounds__(256) void k_gemm(const void* __restrict__ Av,
                                              const unsigned short* __restrict__ Bt,
                                              void* __restrict__ Cout,
                                              int M, int Nc) {
    __shared__ unsigned short As[2][128 * LP];
    __shared__ unsigned short Bs[2][128 * LP];

    const int tid = threadIdx.x;
    const int wave = tid >> 6, lane = tid & 63;
    const int wm = (wave >> 1) * 64, wn = (wave & 1) * 64;
    const int l15 = lane & 15, quad = lane >> 4;
    const int mBase = blockIdx.x * 128, nBase = blockIdx.y * 128;

    f32x4 acc[4][4];
#pragma unroll
    for (int i = 0; i < 4; i++)
#pragma unroll
        for (int j = 0; j < 4; j++) acc[i][j] = (f32x4){0.f, 0.f, 0.f, 0.f};

    const int r0 = tid >> 2, kc0 = tid & 3;       // staged rows r0 and r0+64
    int am0 = mBase + r0;      if (am0 >= M) am0 = M - 1;
    int am1 = mBase + r0 + 64; if (am1 >= M) am1 = M - 1;

    const uint4* Ap0; const uint4* Ap1; const float4* Af0; const float4* Af1;
    if (AF32) {
        Af0 = (const float4*)Av + (size_t)am0 * 64 + kc0 * 2;
        Af1 = (const float4*)Av + (size_t)am1 * 64 + kc0 * 2;
    } else {
        Ap0 = (const uint4*)Av + (size_t)am0 * 32 + kc0;
        Ap1 = (const uint4*)Av + (size_t)am1 * 32 + kc0;
    }
    const uint4* Bp0 = (const uint4*)Bt + (size_t)(nBase + r0) * 32 + kc0;
    const uint4* Bp1 = (const uint4*)Bt + (size_t)(nBase + r0 + 64) * 32 + kc0;

    uint4 a0, a1, b0, b1;
    auto LOAD = [&](int kt) {
        if (AF32) {
            const float4 l0 = Af0[kt * 8], h0 = Af0[kt * 8 + 1];
            const float4 l1 = Af1[kt * 8], h1 = Af1[kt * 8 + 1];
            a0.x = pk_bf16(l0.x, l0.y); a0.y = pk_bf16(l0.z, l0.w);
            a0.z = pk_bf16(h0.x, h0.y); a0.w = pk_bf16(h0.z, h0.w);
            a1.x = pk_bf16(l1.x, l1.y); a1.y = pk_bf16(l1.z, l1.w);
            a1.z = pk_bf16(h1.x, h1.y); a1.w = pk_bf16(h1.z, h1.w);
        } else {
            a0 = Ap0[kt * 4];
            a1 = Ap1[kt * 4];
        }
        b0 = Bp0[kt * 4];
        b1 = Bp1[kt * 4];
    };
    auto STORE = [&](int buf) {
        *(uint4*)&As[buf][r0 * LP + kc0 * 8] = a0;
        *(uint4*)&As[buf][(r0 + 64) * LP + kc0 * 8] = a1;
        *(uint4*)&Bs[buf][r0 * LP + kc0 * 8] = b0;
        *(uint4*)&Bs[buf][(r0 + 64) * LP + kc0 * 8] = b1;
    };

    LOAD(0);
    STORE(0);
    __syncthreads();
    for (int kt = 0; kt < 8; ++kt) {
        const int cur = kt & 1;
        if (kt < 7) LOAD(kt + 1);
        s16x8 af[4], bf[4];
#pragma unroll
        for (int i = 0; i < 4; i++)
            af[i] = *(const s16x8*)&As[cur][(wm + i * 16 + l15) * LP + quad * 8];
#pragma unroll
        for (int j = 0; j < 4; j++)
            bf[j] = *(const s16x8*)&Bs[cur][(wn + j * 16 + l15) * LP + quad * 8];
        if (kt < 7) STORE(cur ^ 1);
#pragma unroll
        for (int i = 0; i < 4; i++)
#pragma unroll
            for (int j = 0; j < 4; j++)
                acc[i][j] = __builtin_amdgcn_mfma_f32_16x16x32_bf16(af[i], bf[j], acc[i][j], 0, 0, 0);
        __syncthreads();
    }

#pragma unroll
    for (int i = 0; i < 4; i++) {
        const int rowb = mBase + wm + i * 16 + quad * 4;
#pragma unroll
        for (int j = 0; j < 4; j++) {
            const int col = nBase + wn + j * 16 + l15;
#pragma unroll
            for (int r = 0; r < 4; r += 2) {
                if (FP8OUT) {
                    const unsigned int pk = __builtin_amdgcn_cvt_pk_fp8_f32(
                        acc[i][j][r], acc[i][j][r + 1], 0, false);
                    if (rowb + r < M)
                        ((unsigned char*)Cout)[(size_t)(rowb + r) * Nc + col] =
                            (unsigned char)pk;
                    if (rowb + r + 1 < M)
                        ((unsigned char*)Cout)[(size_t)(rowb + r + 1) * Nc + col] =
                            (unsigned char)(pk >> 8);
                } else {
                    const unsigned int pk = pk_bf16(acc[i][j][r], acc[i][j][r + 1]);
                    if (rowb + r < M)
                        ((unsigned short*)Cout)[(size_t)(rowb + r) * Nc + col] =
                            (unsigned short)pk;
                    if (rowb + r + 1 < M)
                        ((unsigned short*)Cout)[(size_t)(rowb + r + 1) * Nc + col] =
                            (unsigned short)(pk >> 16);
                }
            }
        }
    }
}

// ---------------- propagation ----------------
// Quarter-wave per edge, 4-deep gather pipeline, branchless weight-zeroed tail.
// w = dinv[src]*dinv[dst] computed on the fly (dinv table is L2-resident).

__global__ void k_prop256f8(const uint4* __restrict__ X4,
                            const int* __restrict__ rowptr,
                            const int* __restrict__ cnt,
                            const int* __restrict__ es,
                            const float* __restrict__ dinv,
                            const float* __restrict__ bias,
                            uint4* __restrict__ Y4, int n) {
    const int wid = (int)((blockIdx.x * blockDim.x + threadIdx.x) >> 6);
    const int lane = threadIdx.x & 63;
    const int quad = lane >> 4, l16 = lane & 15;
    if (wid >= n) return;
    const float dd = dinv[wid];
    f32x2 a[8];
#pragma unroll
    for (int k = 0; k < 8; k++) a[k] = (f32x2){0.f, 0.f};

    const int beg = rowptr[wid];
    const int end = beg + cnt[wid];
    int j = beg + quad;

    auto EDGE = [&](int jj, int& s, float& w) {
        const bool v = jj < end;
        s = es[v ? jj : beg];           // row-local clamp (hot line)
        w = v ? dinv[s] * dd : 0.f;
    };

    int s0, s1, s2, s3;
    float w0, w1, w2, w3;
    EDGE(j, s0, w0); EDGE(j + 4, s1, w1); EDGE(j + 8, s2, w2); EDGE(j + 12, s3, w3);

    if (quad == 0) {
        const uint4 v = X4[(size_t)wid * 16 + l16];
        acc16p(a, v, (f32x2){dd * dd, dd * dd});
    }

    while (j + 12 < end) {
        const uint4 u0 = X4[(size_t)s0 * 16 + l16];
        const uint4 u1 = X4[(size_t)s1 * 16 + l16];
        const uint4 u2 = X4[(size_t)s2 * 16 + l16];
        const uint4 u3 = X4[(size_t)s3 * 16 + l16];
        j += 16;
        int t0, t1, t2, t3;
        float x0, x1, x2, x3;
        EDGE(j, t0, x0); EDGE(j + 4, t1, x1); EDGE(j + 8, t2, x2); EDGE(j + 12, t3, x3);
        acc16p(a, u0, (f32x2){w0, w0});
        acc16p(a, u1, (f32x2){w1, w1});
        acc16p(a, u2, (f32x2){w2, w2});
        acc16p(a, u3, (f32x2){w3, w3});
        s0 = t0; s1 = t1; s2 = t2; s3 = t3;
        w0 = x0; w1 = x1; w2 = x2; w3 = x3;
    }
    {
        const uint4 u0 = X4[(size_t)s0 * 16 + l16];
        const uint4 u1 = X4[(size_t)s1 * 16 + l16];
        const uint4 u2 = X4[(size_t)s2 * 16 + l16];
        acc16p(a, u0, (f32x2){w0, w0});
        acc16p(a, u1, (f32x2){w1, w1});
        acc16p(a, u2, (f32x2){w2, w2});
    }
#pragma unroll
    for (int k = 0; k < 8; k++) {
        a[k][0] += __shfl_xor(a[k][0], 16);
        a[k][1] += __shfl_xor(a[k][1], 16);
        a[k][0] += __shfl_xor(a[k][0], 32);
        a[k][1] += __shfl_xor(a[k][1], 32);
    }
    if (quad == 0) {
        const float4* bp = (const float4*)bias + l16 * 4;
#pragma unroll
        for (int q = 0; q < 4; q++) {
            const float4 b = bp[q];
            a[2 * q][0]     = fmaxf(a[2 * q][0] + b.x, 0.f);
            a[2 * q][1]     = fmaxf(a[2 * q][1] + b.y, 0.f);
            a[2 * q + 1][0] = fmaxf(a[2 * q + 1][0] + b.z, 0.f);
            a[2 * q + 1][1] = fmaxf(a[2 * q + 1][1] + b.w, 0.f);
        }
        uint4 p0, p1;
        p0.x = pk_bf16(a[0][0], a[0][1]);
        p0.y = pk_bf16(a[1][0], a[1][1]);
        p0.z = pk_bf16(a[2][0], a[2][1]);
        p0.w = pk_bf16(a[3][0], a[3][1]);
        p1.x = pk_bf16(a[4][0], a[4][1]);
        p1.y = pk_bf16(a[5][0], a[5][1]);
        p1.z = pk_bf16(a[6][0], a[6][1]);
        p1.w = pk_bf16(a[7][0], a[7][1]);
        Y4[(size_t)wid * 32 + l16 * 2] = p0;
        Y4[(size_t)wid * 32 + l16 * 2 + 1] = p1;
    }
}

__global__ void k_prop128b(const uint4* __restrict__ X4,
                           const int* __restrict__ rowptr,
                           const int* __restrict__ cnt,
                           const int* __restrict__ es,
                           const float* __restrict__ dinv,
                           const float* __restrict__ bias,
                           float* __restrict__ Yout, int n) {
    const int wid = (int)((blockIdx.x * blockDim.x + threadIdx.x) >> 6);
    const int lane = threadIdx.x & 63;
    const int quad = lane >> 4, l16 = lane & 15;
    if (wid >= n) return;
    const float dd = dinv[wid];
    f32x2 a[4];
#pragma unroll
    for (int k = 0; k < 4; k++) a[k] = (f32x2){0.f, 0.f};

    const int beg = rowptr[wid];
    const int end = beg + cnt[wid];
    int j = beg + quad;

    auto EDGE = [&](int jj, int& s, float& w) {
        const bool v = jj < end;
        s = es[v ? jj : beg];
        w = v ? dinv[s] * dd : 0.f;
    };

    int s0, s1, s2, s3;
    float w0, w1, w2, w3;
    EDGE(j, s0, w0); EDGE(j + 4, s1, w1); EDGE(j + 8, s2, w2); EDGE(j + 12, s3, w3);

    if (quad == 0) {
        const uint4 v = X4[(size_t)wid * 16 + l16];
        acc8p(a, v, (f32x2){dd * dd, dd * dd});
    }

    while (j + 12 < end) {
        const uint4 u0 = X4[(size_t)s0 * 16 + l16];
        const uint4 u1 = X4[(size_t)s1 * 16 + l16];
        const uint4 u2 = X4[(size_t)s2 * 16 + l16];
        const uint4 u3 = X4[(size_t)s3 * 16 + l16];
        j += 16;
        int t0, t1, t2, t3;
        float x0, x1, x2, x3;
        EDGE(j, t0, x0); EDGE(j + 4, t1, x1); EDGE(j + 8, t2, x2); EDGE(j + 12, t3, x3);
        acc8p(a, u0, (f32x2){w0, w0});
        acc8p(a, u1, (f32x2){w1, w1});
        acc8p(a, u2, (f32x2){w2, w2});
        acc8p(a, u3, (f32x2){w3, w3});
        s0 = t0; s1 = t1; s2 = t2; s3 = t3;
        w0 = x0; w1 = x1; w2 = x2; w3 = x3;
    }
    {
        const uint4 u0 = X4[(size_t)s0 * 16 + l16];
        const uint4 u1 = X4[(size_t)s1 * 16 + l16];
        const uint4 u2 = X4[(size_t)s2 * 16 + l16];
        acc8p(a, u0, (f32x2){w0, w0});
        acc8p(a, u1, (f32x2){w1, w1});
        acc8p(a, u2, (f32x2){w2, w2});
    }
#pragma unroll
    for (int k = 0; k < 4; k++) {
        a[k][0] += __shfl_xor(a[k][0], 16);
        a[k][1] += __shfl_xor(a[k][1], 16);
        a[k][0] += __shfl_xor(a[k][0], 32);
        a[k][1] += __shfl_xor(a[k][1], 32);
    }
    if (quad == 0) {
        const float4 b0 = ((const float4*)bias)[l16 * 2];
        const float4 b1 = ((const float4*)bias)[l16 * 2 + 1];
        float4* op = (float4*)Yout + (size_t)wid * 32 + l16 * 2;
        op[0] = make_float4(a[0][0] + b0.x, a[0][1] + b0.y, a[1][0] + b0.z, a[1][1] + b0.w);
        op[1] = make_float4(a[2][0] + b1.x, a[2][1] + b1.y, a[3][0] + b1.z, a[3][1] + b1.w);
    }
}

extern "C" void kernel_launch(void* const* d_in, const int* in_sizes, int n_in,
                              void* d_out, int out_size, void* d_ws, size_t ws_size,
                              hipStream_t stream) {
    const float* x  = (const float*)d_in[0];
    const int*   ei = (const int*)d_in[1];
    const float* W1 = (const float*)d_in[2];
    const float* b1 = (const float*)d_in[3];
    const float* W2 = (const float*)d_in[4];
    const float* b2 = (const float*)d_in[5];
    float* out = (float*)d_out;

    const int n = in_sizes[0] / 256;  // 50000
    const int e = in_sizes[1] / 2;    // 1600000
    const int* src = ei;
    const int* dst = ei + e;
    const int nb = (n + 255) >> 8;    // 196 buckets (<=256 required)

    // bucket-local es capacity: 1.5x mean (45+ sigma for random graphs)
    int capE = (((e / nb) * 3 / 2) + 255) & ~255;
    if (capE < 2048) capE = 2048;

    char* wsp = (char*)d_ws;
    size_t off = 0;
    auto alloc = [&](size_t bytes) -> char* {
        char* p = wsp + off;
        off += (bytes + 511) & ~(size_t)511;
        return p;
    };
    float* dinv    = (float*)alloc(sizeof(float) * n);
    int*   rowptr  = (int*)alloc(sizeof(int) * n);
    int*   cnt     = (int*)alloc(sizeof(int) * n);
    int*   bcc     = (int*)alloc(2048);          // bcnt[256] | bcur[256]
    int*   bcnt    = bcc;
    int*   bcur    = bcc + 256;
    int*   es      = (int*)alloc(4ull * (size_t)nb * capE);
    unsigned short* W1t = (unsigned short*)alloc(2ull * 256 * 256); // [N][K]
    unsigned short* W2t = (unsigned short*)alloc(2ull * 128 * 256); // [N][K]
    unsigned char*  T1  = (unsigned char*)alloc((size_t)n * 256);   // x@W1 fp8
    unsigned short* H   = (unsigned short*)alloc(2ull * n * 256);   // relu(prop+b1) bf16
    unsigned short* T2  = (unsigned short*)alloc(2ull * n * 128);   // H@W2 bf16
    // eb (packed (dlow,src), 4B*e = 6.4MB) aliases H (25.6MB):
    // build finishes (k_merged) before H is first written (prop256f8).
    unsigned int* eb = (unsigned int*)H;

    const int nb_t  = (e + TILE - 1) / TILE;      // 782 (hist)
    const int nb_t2 = (e + TILE2 - 1) / TILE2;    // 196 (scatter, fat segments)
    const int tw_b  = (65536 + 32768) / 256;      // 384 transpose blocks

    // ---- build: memset(2KB) + 3 dispatches, ONE eb read ----
    (void)hipMemsetAsync(bcc, 0, 2048, stream);
    k_bhist_tw<<<nb_t + tw_b, 256, 0, stream>>>(dst, bcnt, e, nb, nb_t, W1, W2, W1t, W2t);
    k_bscatter8<<<nb_t2, 256, 0, stream>>>(src, dst, bcnt, bcur, eb, e, nb);
    k_merged<<<nb, 256, 0, stream>>>(eb, bcnt, rowptr, cnt, dinv, es, n, nb, capE);

    // ---- layer 1: T1 = fp8(x@W1) ----
    dim3 g1((n + 127) / 128, 2);
    k_gemm<true, true><<<g1, 256, 0, stream>>>(x, W1t, T1, n, 256);
    k_prop256f8<<<(n + 3) / 4, 256, 0, stream>>>((const uint4*)T1, rowptr, cnt, es,
                                                 dinv, b1, (uint4*)H, n);

    // ---- layer 2: T2 = bf16(H@W2); out = prop(T2)+b2 ----
    dim3 g2((n + 127) / 128, 1);
    k_gemm<false, false><<<g2, 256, 0, stream>>>(H, W2t, T2, n, 128);
    k_prop128b<<<(n + 3) / 4, 256, 0, stream>>>((const uint4*)T2, rowptr, cnt, es,
                                                dinv, b2, out, n);
}

// Round 9
// 317.255 us; speedup vs baseline: 1.1827x; 1.0434x over previous
//
#include <hip/hip_runtime.h>

typedef short s16x8 __attribute__((ext_vector_type(8)));
typedef float f32x4 __attribute__((ext_vector_type(4)));
typedef float f32x2 __attribute__((ext_vector_type(2)));

#define TILE 2048   // edges per block: hist kernel
#define TILE2 8192  // edges per block: scatter kernel (fat segments)

// ---------- bf16 helpers (bit-level, RNE) ----------
__device__ __forceinline__ unsigned int brne(float f) {
    unsigned int u = __float_as_uint(f);
    return (u + 0x7FFFu + ((u >> 16) & 1u)) >> 16;   // bf16 bits in low 16
}
__device__ __forceinline__ float blo(unsigned int u) { return __uint_as_float(u << 16); }
__device__ __forceinline__ float bhi(unsigned int u) { return __uint_as_float(u & 0xFFFF0000u); }

// packed f32x2 -> bf16x2 via HW cvt (RNE)
__device__ __forceinline__ unsigned int pk_bf16(float lo, float hi) {
    unsigned int r;
    asm("v_cvt_pk_bf16_f32 %0, %1, %2" : "=v"(r) : "v"(lo), "v"(hi));
    return r;
}

// packed 2xf32 FMA (VOP3P)
__device__ __forceinline__ void pkfma(f32x2& a, const f32x2 x, const f32x2 w) {
    asm("v_pk_fma_f32 %0, %1, %2, %0" : "+v"(a) : "v"(x), "v"(w));
}

// accumulate 8 bf16 lanes of a uint4 row piece into 4 packed f32x2
__device__ __forceinline__ void acc8p(f32x2* a, const uint4 u, const f32x2 w2) {
    pkfma(a[0], (f32x2){blo(u.x), bhi(u.x)}, w2);
    pkfma(a[1], (f32x2){blo(u.y), bhi(u.y)}, w2);
    pkfma(a[2], (f32x2){blo(u.z), bhi(u.z)}, w2);
    pkfma(a[3], (f32x2){blo(u.w), bhi(u.w)}, w2);
}

// packed accumulate: 16 fp8 of a uint4 into 8 f32x2 accumulators
__device__ __forceinline__ void acc16p(f32x2* a, const uint4 u, const f32x2 w2) {
    pkfma(a[0], __builtin_amdgcn_cvt_pk_f32_fp8((int)u.x, false), w2);
    pkfma(a[1], __builtin_amdgcn_cvt_pk_f32_fp8((int)u.x, true),  w2);
    pkfma(a[2], __builtin_amdgcn_cvt_pk_f32_fp8((int)u.y, false), w2);
    pkfma(a[3], __builtin_amdgcn_cvt_pk_f32_fp8((int)u.y, true),  w2);
    pkfma(a[4], __builtin_amdgcn_cvt_pk_f32_fp8((int)u.z, false), w2);
    pkfma(a[5], __builtin_amdgcn_cvt_pk_f32_fp8((int)u.z, true),  w2);
    pkfma(a[6], __builtin_amdgcn_cvt_pk_f32_fp8((int)u.w, false), w2);
    pkfma(a[7], __builtin_amdgcn_cvt_pk_f32_fp8((int)u.w, true),  w2);
}

// ---------------- binned CSR build ----------------
// bucket = dst >> 8 (256 nodes/bucket). eb entry packed: (dst&255)<<24 | src.
// es layout: bucket-local fixed-capacity regions; rowptr[node] = b*capE + off,
// row end = rowptr[node] + cnt[node]. No cross-bucket prefix needed.

// bucket hist via LDS (blocks [0,nbt)) + weight transposes (blocks >= nbt)
__global__ void k_bhist_tw(const int* __restrict__ dst, int* __restrict__ bcnt,
                           int e, int nb, int nbt,
                           const float* __restrict__ W1, const float* __restrict__ W2,
                           unsigned short* __restrict__ W1t, unsigned short* __restrict__ W2t) {
    const int tid = threadIdx.x;
    if ((int)blockIdx.x >= nbt) {
        const int t = ((int)blockIdx.x - nbt) * 256 + tid;
        if (t < 65536) {
            const int k = t >> 8, nn = t & 255;
            W1t[nn * 256 + k] = (unsigned short)brne(W1[t]);
        } else {
            const int u = t - 65536;
            const int k = u >> 7, nn = u & 127;
            W2t[nn * 256 + k] = (unsigned short)brne(W2[u]);
        }
        return;
    }
    __shared__ int h[256];
    h[tid] = 0;
    __syncthreads();
    const int base = blockIdx.x * TILE + tid;
#pragma unroll
    for (int k = 0; k < 8; k++) {
        const int i = base + k * 256;
        if (i < e) atomicAdd(&h[dst[i] >> 8], 1);
    }
    __syncthreads();
    if (tid < nb && h[tid]) atomicAdd(&bcnt[tid], h[tid]);
}

// scatter into DENSE buckets; TILE2 edges/block -> fat per-bucket segments.
__global__ void k_bscatter8(const int* __restrict__ src, const int* __restrict__ dst,
                            const int* __restrict__ bcnt, int* __restrict__ bcur,
                            unsigned int* __restrict__ eb, int e, int nb) {
    __shared__ int sh[256], h[256], base2[256], h2[256];
    const int tid = threadIdx.x;
    const int v = (tid < nb) ? bcnt[tid] : 0;
    int x = v;
    sh[tid] = x;
    __syncthreads();
    for (int off = 1; off < 256; off <<= 1) {
        const int t = (tid >= off) ? sh[tid - off] : 0;
        __syncthreads();
        if (tid >= off) { x += t; sh[tid] = x; }
        __syncthreads();
    }
    const int sbase = x - v;   // exclusive base for bucket `tid`
    h[tid] = 0; h2[tid] = 0;
    __syncthreads();
    const int beg = blockIdx.x * TILE2;
    const int fin = min(beg + TILE2, e);
    for (int i = beg + tid; i < fin; i += 256)
        atomicAdd(&h[dst[i] >> 8], 1);
    __syncthreads();
    if (h[tid]) base2[tid] = sbase + atomicAdd(&bcur[tid], h[tid]);
    __syncthreads();
    for (int i = beg + tid; i < fin; i += 256) {
        const int s = src[i], d = dst[i];
        const int b = d >> 8;
        const int off = atomicAdd(&h2[b], 1);
        eb[base2[b] + off] = ((unsigned)(d & 255) << 24) | (unsigned)s;
    }
}

// per-bucket node hist + dinv + cnt + bucket-local rowptr (first eb read)
__global__ void k_nhist(const unsigned int* __restrict__ eb, const int* __restrict__ bcnt,
                        int* __restrict__ rowptr, int* __restrict__ cnt,
                        float* __restrict__ dinv, int n, int nb, int capE) {
    __shared__ int sh[256], c[256];
    const int tid = threadIdx.x, b = blockIdx.x;
    const int v0 = (tid < nb) ? bcnt[tid] : 0;
    int x = v0;
    sh[tid] = x;
    __syncthreads();
    for (int off = 1; off < 256; off <<= 1) {
        const int t = (tid >= off) ? sh[tid - off] : 0;
        __syncthreads();
        if (tid >= off) { x += t; sh[tid] = x; }
        __syncthreads();
    }
    const int ebBase = (b > 0) ? sh[b - 1] : 0;
    const int cntB = bcnt[b];
    c[tid] = 0;
    __syncthreads();
    for (int i = tid; i < cntB; i += 256)
        atomicAdd(&c[eb[ebBase + i] >> 24], 1);
    __syncthreads();
    const int v = c[tid];
    const int node = b * 256 + tid;
    if (node < n) {
        dinv[node] = rsqrtf((float)(v + 1));  // deg includes self-loop
        cnt[node] = v;
    }
    int y = v;
    sh[tid] = y;
    __syncthreads();
    for (int off = 1; off < 256; off <<= 1) {
        const int t = (tid >= off) ? sh[tid - off] : 0;
        __syncthreads();
        if (tid >= off) { y += t; sh[tid] = y; }
        __syncthreads();
    }
    if (node < n) rowptr[node] = b * capE + (y - v);
}

// placement with premultiplied weights (second eb read; eb is 6.4MB, L2/L3 hot)
__global__ void k_place(const unsigned int* __restrict__ eb, const int* __restrict__ bcnt,
                        const int* __restrict__ rowptr, const float* __restrict__ dinv,
                        int2* __restrict__ es, int n, int nb) {
    __shared__ int sh[256], rp[256], offs[256];
    __shared__ float sdv[256];
    const int tid = threadIdx.x, b = blockIdx.x;
    const int v0 = (tid < nb) ? bcnt[tid] : 0;
    int x = v0;
    sh[tid] = x;
    __syncthreads();
    for (int off = 1; off < 256; off <<= 1) {
        const int t = (tid >= off) ? sh[tid - off] : 0;
        __syncthreads();
        if (tid >= off) { x += t; sh[tid] = x; }
        __syncthreads();
    }
    const int ebBase = (b > 0) ? sh[b - 1] : 0;
    const int cntB = bcnt[b];
    const int node = b * 256 + tid;
    rp[tid] = (node < n) ? rowptr[node] : 0;
    sdv[tid] = (node < n) ? dinv[node] : 0.f;
    offs[tid] = 0;
    __syncthreads();
    for (int i = tid; i < cntB; i += 256) {
        const unsigned int u = eb[ebBase + i];
        const int d = (int)(u >> 24);
        const int sI = (int)(u & 0xFFFFFFu);
        const float w = dinv[sI] * sdv[d];
        const int local = atomicAdd(&offs[d], 1);
        es[rp[d] + local] = make_int2(sI, __float_as_int(w));
    }
}

// ---------------- MFMA GEMM: C[M,Nc] = A[M,256] @ Bt[Nc,256]^T ----------------
// Double-buffered LDS, 1 barrier per K-step.
#define LP 40
template <bool AF32, bool FP8OUT>
__global__ __launch_bounds__(256) void k_gemm(const void* __restrict__ Av,
                                              const unsigned short* __restrict__ Bt,
                                              void* __restrict__ Cout,
                                              int M, int Nc) {
    __shared__ unsigned short As[2][128 * LP];
    __shared__ unsigned short Bs[2][128 * LP];

    const int tid = threadIdx.x;
    const int wave = tid >> 6, lane = tid & 63;
    const int wm = (wave >> 1) * 64, wn = (wave & 1) * 64;
    const int l15 = lane & 15, quad = lane >> 4;
    const int mBase = blockIdx.x * 128, nBase = blockIdx.y * 128;

    f32x4 acc[4][4];
#pragma unroll
    for (int i = 0; i < 4; i++)
#pragma unroll
        for (int j = 0; j < 4; j++) acc[i][j] = (f32x4){0.f, 0.f, 0.f, 0.f};

    const int r0 = tid >> 2, kc0 = tid & 3;       // staged rows r0 and r0+64
    int am0 = mBase + r0;      if (am0 >= M) am0 = M - 1;
    int am1 = mBase + r0 + 64; if (am1 >= M) am1 = M - 1;

    const uint4* Ap0; const uint4* Ap1; const float4* Af0; const float4* Af1;
    if (AF32) {
        Af0 = (const float4*)Av + (size_t)am0 * 64 + kc0 * 2;
        Af1 = (const float4*)Av + (size_t)am1 * 64 + kc0 * 2;
    } else {
        Ap0 = (const uint4*)Av + (size_t)am0 * 32 + kc0;
        Ap1 = (const uint4*)Av + (size_t)am1 * 32 + kc0;
    }
    const uint4* Bp0 = (const uint4*)Bt + (size_t)(nBase + r0) * 32 + kc0;
    const uint4* Bp1 = (const uint4*)Bt + (size_t)(nBase + r0 + 64) * 32 + kc0;

    uint4 a0, a1, b0, b1;
    auto LOAD = [&](int kt) {
        if (AF32) {
            const float4 l0 = Af0[kt * 8], h0 = Af0[kt * 8 + 1];
            const float4 l1 = Af1[kt * 8], h1 = Af1[kt * 8 + 1];
            a0.x = pk_bf16(l0.x, l0.y); a0.y = pk_bf16(l0.z, l0.w);
            a0.z = pk_bf16(h0.x, h0.y); a0.w = pk_bf16(h0.z, h0.w);
            a1.x = pk_bf16(l1.x, l1.y); a1.y = pk_bf16(l1.z, l1.w);
            a1.z = pk_bf16(h1.x, h1.y); a1.w = pk_bf16(h1.z, h1.w);
        } else {
            a0 = Ap0[kt * 4];
            a1 = Ap1[kt * 4];
        }
        b0 = Bp0[kt * 4];
        b1 = Bp1[kt * 4];
    };
    auto STORE = [&](int buf) {
        *(uint4*)&As[buf][r0 * LP + kc0 * 8] = a0;
        *(uint4*)&As[buf][(r0 + 64) * LP + kc0 * 8] = a1;
        *(uint4*)&Bs[buf][r0 * LP + kc0 * 8] = b0;
        *(uint4*)&Bs[buf][(r0 + 64) * LP + kc0 * 8] = b1;
    };

    LOAD(0);
    STORE(0);
    __syncthreads();
    for (int kt = 0; kt < 8; ++kt) {
        const int cur = kt & 1;
        if (kt < 7) LOAD(kt + 1);
        s16x8 af[4], bf[4];
#pragma unroll
        for (int i = 0; i < 4; i++)
            af[i] = *(const s16x8*)&As[cur][(wm + i * 16 + l15) * LP + quad * 8];
#pragma unroll
        for (int j = 0; j < 4; j++)
            bf[j] = *(const s16x8*)&Bs[cur][(wn + j * 16 + l15) * LP + quad * 8];
        if (kt < 7) STORE(cur ^ 1);
#pragma unroll
        for (int i = 0; i < 4; i++)
#pragma unroll
            for (int j = 0; j < 4; j++)
                acc[i][j] = __builtin_amdgcn_mfma_f32_16x16x32_bf16(af[i], bf[j], acc[i][j], 0, 0, 0);
        __syncthreads();
    }

#pragma unroll
    for (int i = 0; i < 4; i++) {
        const int rowb = mBase + wm + i * 16 + quad * 4;
#pragma unroll
        for (int j = 0; j < 4; j++) {
            const int col = nBase + wn + j * 16 + l15;
#pragma unroll
            for (int r = 0; r < 4; r += 2) {
                if (FP8OUT) {
                    const unsigned int pk = __builtin_amdgcn_cvt_pk_fp8_f32(
                        acc[i][j][r], acc[i][j][r + 1], 0, false);
                    if (rowb + r < M)
                        ((unsigned char*)Cout)[(size_t)(rowb + r) * Nc + col] =
                            (unsigned char)pk;
                    if (rowb + r + 1 < M)
                        ((unsigned char*)Cout)[(size_t)(rowb + r + 1) * Nc + col] =
                            (unsigned char)(pk >> 8);
                } else {
                    const unsigned int pk = pk_bf16(acc[i][j][r], acc[i][j][r + 1]);
                    if (rowb + r < M)
                        ((unsigned short*)Cout)[(size_t)(rowb + r) * Nc + col] =
                            (unsigned short)pk;
                    if (rowb + r + 1 < M)
                        ((unsigned short*)Cout)[(size_t)(rowb + r + 1) * Nc + col] =
                            (unsigned short)(pk >> 16);
                }
            }
        }
    }
}

// ---------------- propagation ----------------
// Quarter-wave per edge, 4-deep gather pipeline, premultiplied edge weights.

__global__ void k_prop256f8(const uint4* __restrict__ X4,
                            const int* __restrict__ rowptr,
                            const int* __restrict__ cnt,
                            const int2* __restrict__ es2,
                            const float* __restrict__ dinv,
                            const float* __restrict__ bias,
                            uint4* __restrict__ Y4, int n) {
    const int wid = (int)((blockIdx.x * blockDim.x + threadIdx.x) >> 6);
    const int lane = threadIdx.x & 63;
    const int quad = lane >> 4, l16 = lane & 15;
    if (wid >= n) return;
    const float dd = dinv[wid];
    f32x2 a[8];
#pragma unroll
    for (int k = 0; k < 8; k++) a[k] = (f32x2){0.f, 0.f};

    const int beg = rowptr[wid];
    const int end = beg + cnt[wid];
    int j = beg + quad;

    auto EDGE = [&](int jj, int& s, float& w) {
        const bool v = jj < end;
        const int2 p = es2[v ? jj : beg];   // beg always within es region
        s = v ? p.x : 0;                    // mask s: gaps are uninitialized
        w = v ? __int_as_float(p.y) : 0.f;
    };

    int s0, s1, s2, s3;
    float w0, w1, w2, w3;
    EDGE(j, s0, w0); EDGE(j + 4, s1, w1); EDGE(j + 8, s2, w2); EDGE(j + 12, s3, w3);

    if (quad == 0) {
        const uint4 v = X4[(size_t)wid * 16 + l16];
        acc16p(a, v, (f32x2){dd * dd, dd * dd});
    }

    while (j + 12 < end) {
        const uint4 u0 = X4[(size_t)s0 * 16 + l16];
        const uint4 u1 = X4[(size_t)s1 * 16 + l16];
        const uint4 u2 = X4[(size_t)s2 * 16 + l16];
        const uint4 u3 = X4[(size_t)s3 * 16 + l16];
        j += 16;
        int t0, t1, t2, t3;
        float x0, x1, x2, x3;
        EDGE(j, t0, x0); EDGE(j + 4, t1, x1); EDGE(j + 8, t2, x2); EDGE(j + 12, t3, x3);
        acc16p(a, u0, (f32x2){w0, w0});
        acc16p(a, u1, (f32x2){w1, w1});
        acc16p(a, u2, (f32x2){w2, w2});
        acc16p(a, u3, (f32x2){w3, w3});
        s0 = t0; s1 = t1; s2 = t2; s3 = t3;
        w0 = x0; w1 = x1; w2 = x2; w3 = x3;
    }
    {
        const uint4 u0 = X4[(size_t)s0 * 16 + l16];
        const uint4 u1 = X4[(size_t)s1 * 16 + l16];
        const uint4 u2 = X4[(size_t)s2 * 16 + l16];
        acc16p(a, u0, (f32x2){w0, w0});
        acc16p(a, u1, (f32x2){w1, w1});
        acc16p(a, u2, (f32x2){w2, w2});
    }
#pragma unroll
    for (int k = 0; k < 8; k++) {
        a[k][0] += __shfl_xor(a[k][0], 16);
        a[k][1] += __shfl_xor(a[k][1], 16);
        a[k][0] += __shfl_xor(a[k][0], 32);
        a[k][1] += __shfl_xor(a[k][1], 32);
    }
    if (quad == 0) {
        const float4* bp = (const float4*)bias + l16 * 4;
#pragma unroll
        for (int q = 0; q < 4; q++) {
            const float4 b = bp[q];
            a[2 * q][0]     = fmaxf(a[2 * q][0] + b.x, 0.f);
            a[2 * q][1]     = fmaxf(a[2 * q][1] + b.y, 0.f);
            a[2 * q + 1][0] = fmaxf(a[2 * q + 1][0] + b.z, 0.f);
            a[2 * q + 1][1] = fmaxf(a[2 * q + 1][1] + b.w, 0.f);
        }
        uint4 p0, p1;
        p0.x = pk_bf16(a[0][0], a[0][1]);
        p0.y = pk_bf16(a[1][0], a[1][1]);
        p0.z = pk_bf16(a[2][0], a[2][1]);
        p0.w = pk_bf16(a[3][0], a[3][1]);
        p1.x = pk_bf16(a[4][0], a[4][1]);
        p1.y = pk_bf16(a[5][0], a[5][1]);
        p1.z = pk_bf16(a[6][0], a[6][1]);
        p1.w = pk_bf16(a[7][0], a[7][1]);
        Y4[(size_t)wid * 32 + l16 * 2] = p0;
        Y4[(size_t)wid * 32 + l16 * 2 + 1] = p1;
    }
}

__global__ void k_prop128b(const uint4* __restrict__ X4,
                           const int* __restrict__ rowptr,
                           const int* __restrict__ cnt,
                           const int2* __restrict__ es2,
                           const float* __restrict__ dinv,
                           const float* __restrict__ bias,
                           float* __restrict__ Yout, int n) {
    const int wid = (int)((blockIdx.x * blockDim.x + threadIdx.x) >> 6);
    const int lane = threadIdx.x & 63;
    const int quad = lane >> 4, l16 = lane & 15;
    if (wid >= n) return;
    const float dd = dinv[wid];
    f32x2 a[4];
#pragma unroll
    for (int k = 0; k < 4; k++) a[k] = (f32x2){0.f, 0.f};

    const int beg = rowptr[wid];
    const int end = beg + cnt[wid];
    int j = beg + quad;

    auto EDGE = [&](int jj, int& s, float& w) {
        const bool v = jj < end;
        const int2 p = es2[v ? jj : beg];
        s = v ? p.x : 0;
        w = v ? __int_as_float(p.y) : 0.f;
    };

    int s0, s1, s2, s3;
    float w0, w1, w2, w3;
    EDGE(j, s0, w0); EDGE(j + 4, s1, w1); EDGE(j + 8, s2, w2); EDGE(j + 12, s3, w3);

    if (quad == 0) {
        const uint4 v = X4[(size_t)wid * 16 + l16];
        acc8p(a, v, (f32x2){dd * dd, dd * dd});
    }

    while (j + 12 < end) {
        const uint4 u0 = X4[(size_t)s0 * 16 + l16];
        const uint4 u1 = X4[(size_t)s1 * 16 + l16];
        const uint4 u2 = X4[(size_t)s2 * 16 + l16];
        const uint4 u3 = X4[(size_t)s3 * 16 + l16];
        j += 16;
        int t0, t1, t2, t3;
        float x0, x1, x2, x3;
        EDGE(j, t0, x0); EDGE(j + 4, t1, x1); EDGE(j + 8, t2, x2); EDGE(j + 12, t3, x3);
        acc8p(a, u0, (f32x2){w0, w0});
        acc8p(a, u1, (f32x2){w1, w1});
        acc8p(a, u2, (f32x2){w2, w2});
        acc8p(a, u3, (f32x2){w3, w3});
        s0 = t0; s1 = t1; s2 = t2; s3 = t3;
        w0 = x0; w1 = x1; w2 = x2; w3 = x3;
    }
    {
        const uint4 u0 = X4[(size_t)s0 * 16 + l16];
        const uint4 u1 = X4[(size_t)s1 * 16 + l16];
        const uint4 u2 = X4[(size_t)s2 * 16 + l16];
        acc8p(a, u0, (f32x2){w0, w0});
        acc8p(a, u1, (f32x2){w1, w1});
        acc8p(a, u2, (f32x2){w2, w2});
    }
#pragma unroll
    for (int k = 0; k < 4; k++) {
        a[k][0] += __shfl_xor(a[k][0], 16);
        a[k][1] += __shfl_xor(a[k][1], 16);
        a[k][0] += __shfl_xor(a[k][0], 32);
        a[k][1] += __shfl_xor(a[k][1], 32);
    }
    if (quad == 0) {
        const float4 b0 = ((const float4*)bias)[l16 * 2];
        const float4 b1 = ((const float4*)bias)[l16 * 2 + 1];
        float4* op = (float4*)Yout + (size_t)wid * 32 + l16 * 2;
        op[0] = make_float4(a[0][0] + b0.x, a[0][1] + b0.y, a[1][0] + b0.z, a[1][1] + b0.w);
        op[1] = make_float4(a[2][0] + b1.x, a[2][1] + b1.y, a[3][0] + b1.z, a[3][1] + b1.w);
    }
}

extern "C" void kernel_launch(void* const* d_in, const int* in_sizes, int n_in,
                              void* d_out, int out_size, void* d_ws, size_t ws_size,
                              hipStream_t stream) {
    const float* x  = (const float*)d_in[0];
    const int*   ei = (const int*)d_in[1];
    const float* W1 = (const float*)d_in[2];
    const float* b1 = (const float*)d_in[3];
    const float* W2 = (const float*)d_in[4];
    const float* b2 = (const float*)d_in[5];
    float* out = (float*)d_out;

    const int n = in_sizes[0] / 256;  // 50000
    const int e = in_sizes[1] / 2;    // 1600000
    const int* src = ei;
    const int* dst = ei + e;
    const int nb = (n + 255) >> 8;    // 196 buckets (<=256 required)

    // bucket-local es capacity: 1.5x mean (45+ sigma for random graphs)
    int capE = (((e / nb) * 3 / 2) + 255) & ~255;
    if (capE < 2048) capE = 2048;

    char* wsp = (char*)d_ws;
    size_t off = 0;
    auto alloc = [&](size_t bytes) -> char* {
        char* p = wsp + off;
        off += (bytes + 511) & ~(size_t)511;
        return p;
    };
    float* dinv    = (float*)alloc(sizeof(float) * n);
    int*   rowptr  = (int*)alloc(sizeof(int) * n);
    int*   cnt     = (int*)alloc(sizeof(int) * n);
    int*   bcc     = (int*)alloc(2048);          // bcnt[256] | bcur[256]
    int*   bcnt    = bcc;
    int*   bcur    = bcc + 256;
    int2*  es      = (int2*)alloc(8ull * (size_t)nb * capE);
    unsigned short* W1t = (unsigned short*)alloc(2ull * 256 * 256); // [N][K]
    unsigned short* W2t = (unsigned short*)alloc(2ull * 128 * 256); // [N][K]
    unsigned char*  T1  = (unsigned char*)alloc((size_t)n * 256);   // x@W1 fp8
    unsigned short* H   = (unsigned short*)alloc(2ull * n * 256);   // relu(prop+b1) bf16
    unsigned short* T2  = (unsigned short*)alloc(2ull * n * 128);   // H@W2 bf16
    // eb (packed (dlow,src), 4B*e = 6.4MB) aliases H (25.6MB):
    // build finishes (k_place) before H is first written (prop256f8).
    unsigned int* eb = (unsigned int*)H;

    const int nb_t  = (e + TILE - 1) / TILE;      // 782 (hist)
    const int nb_t2 = (e + TILE2 - 1) / TILE2;    // 196 (scatter, fat segments)
    const int tw_b  = (65536 + 32768) / 256;      // 384 transpose blocks

    // ---- build: memset(2KB) + 4 dispatches ----
    (void)hipMemsetAsync(bcc, 0, 2048, stream);
    k_bhist_tw<<<nb_t + tw_b, 256, 0, stream>>>(dst, bcnt, e, nb, nb_t, W1, W2, W1t, W2t);
    k_bscatter8<<<nb_t2, 256, 0, stream>>>(src, dst, bcnt, bcur, eb, e, nb);
    k_nhist<<<nb, 256, 0, stream>>>(eb, bcnt, rowptr, cnt, dinv, n, nb, capE);
    k_place<<<nb, 256, 0, stream>>>(eb, bcnt, rowptr, dinv, es, n, nb);

    // ---- layer 1: T1 = fp8(x@W1) ----
    dim3 g1((n + 127) / 128, 2);
    k_gemm<true, true><<<g1, 256, 0, stream>>>(x, W1t, T1, n, 256);
    k_prop256f8<<<(n + 3) / 4, 256, 0, stream>>>((const uint4*)T1, rowptr, cnt, es,
                                                 dinv, b1, (uint4*)H, n);

    // ---- layer 2: T2 = bf16(H@W2); out = prop(T2)+b2 ----
    dim3 g2((n + 127) / 128, 1);
    k_gemm<false, false><<<g2, 256, 0, stream>>>(H, W2t, T2, n, 128);
    k_prop128b<<<(n + 3) / 4, 256, 0, stream>>>((const uint4*)T2, rowptr, cnt, es,
                                                dinv, b2, out, n);
}